// Round 8
// baseline (130.734 us; speedup 1.0000x reference)
//
#include <hip/hip_runtime.h>

#define Wd 64
#define Hd 64
#define HWp 4096
#define CIN_ 128
#define COUT_ 128

typedef _Float16 f16;
typedef _Float16 h2    __attribute__((ext_vector_type(2)));
typedef _Float16 f16x8 __attribute__((ext_vector_type(8)));
typedef float f32x4    __attribute__((ext_vector_type(4)));

__device__ inline ushort f2h(float f) {
    f16 h = (f16)f;
    return __builtin_bit_cast(ushort, h);
}
__device__ inline h2 gb(const int4& g, int d) {
    return __builtin_bit_cast(h2, (&g.x)[d]);
}
__device__ inline h2 dup(float f) {
    f16 h = (f16)f;
    h2 r; r[0] = h; r[1] = h;
    return r;
}
struct H8 { h2 r[4]; };

// ---------------------------------------------------------------------------
// K_prep (1344 blocks): unchanged.
// ---------------------------------------------------------------------------
__global__ __launch_bounds__(256) void prep_offsets_kernel(
    const float* __restrict__ x, const float* __restrict__ w,
    const float* __restrict__ w_off, const float* __restrict__ b_off,
    ushort* __restrict__ xt, ushort* __restrict__ w_t2,
    float4* __restrict__ der)
{
    __shared__ char smem[34816];
    int blk = blockIdx.x;
    int t = threadIdx.x;

    if (blk < 256) {
        ushort* tile = (ushort*)smem;                 // [128][136]
        int b = blk >> 5, yx0 = (blk & 31) << 7;
        const float* xb = x + (size_t)b * CIN_ * HWp + yx0;
        int lanelo = t & 31, grp = t >> 5;
        #pragma unroll
        for (int i = 0; i < 4; i++) {
            int cbase = i * 32 + grp * 4;
            float4 v0 = *(const float4*)(xb + (size_t)(cbase + 0) * HWp + lanelo * 4);
            float4 v1 = *(const float4*)(xb + (size_t)(cbase + 1) * HWp + lanelo * 4);
            float4 v2 = *(const float4*)(xb + (size_t)(cbase + 2) * HWp + lanelo * 4);
            float4 v3 = *(const float4*)(xb + (size_t)(cbase + 3) * HWp + lanelo * 4);
            ushort4 u;
            u.x = f2h(v0.x); u.y = f2h(v1.x); u.z = f2h(v2.x); u.w = f2h(v3.x);
            *(ushort4*)&tile[(lanelo * 4 + 0) * 136 + cbase] = u;
            u.x = f2h(v0.y); u.y = f2h(v1.y); u.z = f2h(v2.y); u.w = f2h(v3.y);
            *(ushort4*)&tile[(lanelo * 4 + 1) * 136 + cbase] = u;
            u.x = f2h(v0.z); u.y = f2h(v1.z); u.z = f2h(v2.z); u.w = f2h(v3.z);
            *(ushort4*)&tile[(lanelo * 4 + 2) * 136 + cbase] = u;
            u.x = f2h(v0.w); u.y = f2h(v1.w); u.z = f2h(v2.w); u.w = f2h(v3.w);
            *(ushort4*)&tile[(lanelo * 4 + 3) * 136 + cbase] = u;
        }
        __syncthreads();
        ushort* dst = xt + ((size_t)b * HWp + yx0) * CIN_;
        int c8 = (t & 15) * 8, yxg = t >> 4;
        #pragma unroll
        for (int i = 0; i < 8; i++) {
            int yxl = i * 16 + yxg;
            int4 v = *(int4*)&tile[yxl * 136 + c8];
            *(int4*)(dst + (size_t)yxl * CIN_ + c8) = v;
        }
    } else if (blk < 832) {
        int i = (blk - 256) * 256 + t;               // 147456 total
        int j    = i & 7;
        int lane = (i >> 3) & 63;
        int ii   = (i >> 9) & 3;
        int wm   = (i >> 11) & 1;
        int s    = i >> 12;
        int o = wm * 64 + ii * 16 + (lane & 15);
        int c = (s & 3) * 32 + (lane >> 4) * 8 + j;
        int k = s >> 2;
        w_t2[i] = f2h(w[o * 1152 + c * 9 + k]);
    } else {
        float* wl   = (float*)smem;                   // 4608 f
        float* part = (float*)(smem + 18432);         // 1024 f
        int blk2 = blk - 832;
        int b = blk2 >> 6;
        int h = blk2 & 63;

        for (int i = t; i < 4608; i += 256) {
            int j = i / 1152;
            int r = i - j * 1152;                     // c*9 + tap
            wl[r * 4 + j] = w_off[i];
        }
        __syncthreads();

        int pi = t & 63, cc = t >> 6;
        const float* xb = x + (size_t)(b * CIN_ + cc * 32) * HWp;

        int idx9[9];
        float msk9[9];
        #pragma unroll
        for (int dy = 0; dy < 3; dy++) {
            int hy = h + dy - 1;
            int hyc = min(max(hy, 0), Hd - 1);
            bool vr = (hy >= 0) && (hy < Hd);
            #pragma unroll
            for (int dx = 0; dx < 3; dx++) {
                int wx = pi + dx - 1;
                int wxc = min(max(wx, 0), Wd - 1);
                bool v = vr && (wx >= 0) && (wx < Wd);
                idx9[dy * 3 + dx] = hyc * Wd + wxc;
                msk9[dy * 3 + dx] = v ? 1.0f : 0.0f;
            }
        }

        float o0 = 0.f, o1 = 0.f, o2 = 0.f, o3 = 0.f;
        #pragma unroll 4
        for (int c = 0; c < 32; c++) {
            const float* xp = xb + c * HWp;
            const float* wc = &wl[(cc * 32 + c) * 36];
            float xv[9];
            #pragma unroll
            for (int tp = 0; tp < 9; tp++) xv[tp] = xp[idx9[tp]] * msk9[tp];
            #pragma unroll
            for (int tp = 0; tp < 9; tp++) {
                float4 wj = *(const float4*)&wc[tp * 4];
                o0 += xv[tp] * wj.x; o1 += xv[tp] * wj.y;
                o2 += xv[tp] * wj.z; o3 += xv[tp] * wj.w;
            }
        }
        part[t * 4 + 0] = o0;
        part[t * 4 + 1] = o1;
        part[t * 4 + 2] = o2;
        part[t * 4 + 3] = o3;
        __syncthreads();

        if (t < 64) {
            float s0 = b_off[0], s1 = b_off[1], s2 = b_off[2], s3 = b_off[3];
            #pragma unroll
            for (int q = 0; q < 4; q++) {
                s0 += part[(q * 64 + t) * 4 + 0];
                s1 += part[(q * 64 + t) * 4 + 1];
                s2 += part[(q * 64 + t) * 4 + 2];
                s3 += part[(q * 64 + t) * 4 + 3];
            }
            float4 d;
            d.x = s0;
            d.y = s1;
            d.z = fmaxf(s2, 0.f) + 1.f;
            d.w = fmaxf(s3, 0.f) + 1.f;
            der[(size_t)b * HWp + h * Wd + t] = d;
        }
    }
}

// ---------------------------------------------------------------------------
// K3: register-direct B-fragments, SCRATCH-PROOF gather pipeline.
// Round-7 diagnosis: VGPR=76 < live-set (~100) + 5.8 MB of non-output HBM
// writes => the 4-buffer int4[4] gather ring spilled to scratch; every
// "prefetch" was a scratch round-trip (MfmaUtil 7.5%). Fix:
//  - 8 NAMED int4 scalars (GA0..3, GB0..3), combine takes them BY VALUE ->
//    compiler cannot demote to scratch. Live set ~72 VGPR + 32 AGPR acc.
//  - consume-then-reissue-same-buffer schedule: combine(GA=2ST) ->
//    issue GA<-2ST+2 -> combine(GB=2ST+1) -> issue GB<-2ST+3 : each refill
//    lands 300-500 cy before reuse (r6's failure mode was ~130 cy slack).
//  - counted vmcnt(8) at the barrier drains only stageA (pinned first);
//    8 gathers ride across the barrier.
// ---------------------------------------------------------------------------
__global__ __launch_bounds__(256, 2) void deform_gemm_mfma(
    const ushort* __restrict__ xt, const ushort* __restrict__ w_t2,
    const float* __restrict__ bias, const float4* __restrict__ der,
    float* __restrict__ out)
{
    __shared__ ushort A_lds[2][2][4096];      // 32 KiB: [buf][chunk][8 otile * 512]
    __shared__ int4 MI[9][64];                // 9 KiB corner byte-offsets (pos<<8)
    __shared__ int4 MW[9][64];                // 9 KiB dup-f16 weights (H8)

    int t = threadIdx.x;
    int b = blockIdx.x & 7;                   // XCD-local batch
    int rp = blockIdx.x >> 3;                 // 0..63
    int p0 = rp << 6;
    const char* xtb = (const char*)(xt + (size_t)b * HWp * CIN_);

    int wv = t >> 6, lane = t & 63;           // 4 waves
    int lm = lane & 15, lq = lane >> 4;
    int myp = wv * 16 + lm;                   // this lane's p within tile
    int lqb = lq * 16;                        // byte offset of its 8-chan slice

    f32x4 acc[8] = {};

    // ---- one-time meta: 4 threads per p split the 9 taps -------------------
    {
        int p = t >> 2;
        int pg = p0 + p;
        float fh = (float)(pg >> 6), fp = (float)(pg & 63);
        float4 dv = der[(size_t)b * HWp + pg];   // {sy, sx, sc1, sc2}
        for (int k = (t & 3); k < 9; k += 4) {
            int ky = (k * 11) >> 5;              // k/3 for 0..8
            int kx = k - ky * 3;
            float by = (float)(ky - 1), bx = (float)(kx - 1);
            bool corner = (ky != 1) && (kx != 1);
            bool edge = (ky != 1) ^ (kx != 1);
            float sk = corner ? dv.z : (edge ? dv.w : 0.0f);
            float py = fh + by * sk + dv.x;
            float px = fp + bx * sk + dv.y;
            float y0f = floorf(py), x0f = floorf(px);
            float wy = py - y0f, wx = px - x0f;
            int y0 = (int)y0f, x0 = (int)x0f;
            int y1 = y0 + 1, x1 = x0 + 1;
            float vy0 = (y0 >= 0 && y0 < Hd) ? 1.f : 0.f;
            float vy1 = (y1 >= 0 && y1 < Hd) ? 1.f : 0.f;
            float vx0 = (x0 >= 0 && x0 < Wd) ? 1.f : 0.f;
            float vx1 = (x1 >= 0 && x1 < Wd) ? 1.f : 0.f;
            int cy0 = min(max(y0, 0), Hd - 1), cy1 = min(max(y1, 0), Hd - 1);
            int cx0 = min(max(x0, 0), Wd - 1), cx1 = min(max(x1, 0), Wd - 1);
            int4 ii;
            ii.x = (cy0 * Wd + cx0) << 8;        // * CIN_ * 2 bytes
            ii.y = (cy0 * Wd + cx1) << 8;
            ii.z = (cy1 * Wd + cx0) << 8;
            ii.w = (cy1 * Wd + cx1) << 8;
            MI[k][p] = ii;
            H8 hw;
            hw.r[0] = dup((1.f - wy) * (1.f - wx) * vy0 * vx0);
            hw.r[1] = dup((1.f - wy) * wx * vy0 * vx1);
            hw.r[2] = dup(wy * (1.f - wx) * vy1 * vx0);
            hw.r[3] = dup(wy * wx * vy1 * vx1);
            MW[k][p] = __builtin_bit_cast(int4, hw);
        }
    }
    __syncthreads();

    int vo0, vo1, vo2, vo3;          // per-lane corner byte offsets (cur tap)

    // async A staging: stage st covers w_t2 ushorts [st*8192, st*8192+8192).
    auto stageA = [&](int buf, int st) {
        const ushort* src = w_t2 + (size_t)st * 8192;
        #pragma unroll
        for (int cc = 0; cc < 2; cc++) {
            #pragma unroll
            for (int hrow = 0; hrow < 2; hrow++) {
                const ushort* g = src + cc * 4096 + (wv * 2 + hrow) * 512 + lane * 8;
                ushort* l = &A_lds[buf][cc][(wv * 2 + hrow) * 512];
                __builtin_amdgcn_global_load_lds(
                    (const __attribute__((address_space(1))) unsigned int*)g,
                    (__attribute__((address_space(3))) unsigned int*)l, 16, 0, 0);
            }
        }
    };

    // combine 4 corners (BY VALUE - register-guaranteed) -> B-frag -> 8 MFMAs
    auto cmbMfma = [&](int cur, int cc, int4 Gx0, int4 Gx1, int4 Gx2, int4 Gx3,
                       const H8& cw) {
        H8 tmp;
        #pragma unroll
        for (int d = 0; d < 4; d++) {
            h2 r = gb(Gx0, d) * cw.r[0];
            r = gb(Gx1, d) * cw.r[1] + r;
            r = gb(Gx2, d) * cw.r[2] + r;
            r = gb(Gx3, d) * cw.r[3] + r;
            tmp.r[d] = r;
        }
        f16x8 bf = __builtin_bit_cast(f16x8, tmp);
        __builtin_amdgcn_s_setprio(1);
        #pragma unroll
        for (int i = 0; i < 8; i++) {
            f16x8 af = *(const f16x8*)&A_lds[cur][cc][i * 512 + lane * 8];
            acc[i] = __builtin_amdgcn_mfma_f32_16x16x32_f16(af, bf, acc[i], 0, 0, 0);
        }
        __builtin_amdgcn_s_setprio(0);
    };

    int4 GA0, GA1, GA2, GA3;         // named scalars: chunk 2ST
    int4 GB0, GB1, GB2, GB3;         //                chunk 2ST+1
    H8 cwA, cwB;
    int4 idxN;

#define ISSUE(G_0, G_1, G_2, G_3, QM)                                        \
    {                                                                        \
        int off_ = (QM) * 64;                                                \
        G_0 = *(const int4*)(xtb + (vo0 + off_));                            \
        G_1 = *(const int4*)(xtb + (vo1 + off_));                            \
        G_2 = *(const int4*)(xtb + (vo2 + off_));                            \
        G_3 = *(const int4*)(xtb + (vo3 + off_));                            \
    }

    // prologue: tap0 meta -> regs; A stage0 (pinned first); gather chunks 0,1.
    {
        int4 mi0 = MI[0][myp];
        vo0 = mi0.x + lqb; vo1 = mi0.y + lqb; vo2 = mi0.z + lqb; vo3 = mi0.w + lqb;
        cwA = __builtin_bit_cast(H8, MW[0][myp]);
        idxN = MI[1][myp];
    }
    stageA(0, 0);
    __builtin_amdgcn_sched_barrier(0);
    ISSUE(GA0, GA1, GA2, GA3, 0)
    ISSUE(GB0, GB1, GB2, GB3, 1)
    __builtin_amdgcn_sched_barrier(0);
    asm volatile("s_waitcnt vmcnt(8)" ::: "memory");   // A0 done; GA,GB ride
    __builtin_amdgcn_s_barrier();
    __builtin_amdgcn_sched_barrier(0);

// Stage ST: stageA(ST+1) pinned first. DORD (odd ST): advance vo to tap
// (ST+1)/2 from reg-prefetched idxN. Then: combine GA(chunk 2ST) -> reissue
// GA<-chunk 2ST+2 -> combine GB(2ST+1) -> reissue GB<-2ST+3 -> refill
// idxN/CWN (odd ST) -> vmcnt(8) (drains stageA only, 8 gathers ride the
// barrier). Compiler inserts exact counted waits before each combine.
#define SBODY(ST, CWC, CWN, DORD)                                            \
    {                                                                        \
        int cur_ = (ST) & 1, nb_ = cur_ ^ 1;                                 \
        stageA(nb_, (ST) + 1);                                               \
        __builtin_amdgcn_sched_barrier(0);                                   \
        if (DORD) {                                                          \
            vo0 = idxN.x + lqb; vo1 = idxN.y + lqb;                          \
            vo2 = idxN.z + lqb; vo3 = idxN.w + lqb;                          \
        }                                                                    \
        cmbMfma(cur_, 0, GA0, GA1, GA2, GA3, CWC);                           \
        ISSUE(GA0, GA1, GA2, GA3, (2 * (ST) + 2) & 3)                        \
        cmbMfma(cur_, 1, GB0, GB1, GB2, GB3, CWC);                           \
        ISSUE(GB0, GB1, GB2, GB3, (2 * (ST) + 3) & 3)                        \
        if (DORD) {                                                          \
            idxN = MI[min(((ST) >> 1) + 2, 8)][myp];                         \
            CWN  = __builtin_bit_cast(H8, MW[min(((ST) >> 1) + 1, 8)][myp]); \
        }                                                                    \
        __builtin_amdgcn_sched_barrier(0);                                   \
        asm volatile("s_waitcnt vmcnt(8)" ::: "memory");                     \
        __builtin_amdgcn_s_barrier();                                        \
        __builtin_amdgcn_sched_barrier(0);                                   \
    }

    for (int su = 0; su < 4; su++) {
        int st = su << 2;
        SBODY(st,     cwA, cwB, 0);
        SBODY(st + 1, cwA, cwB, 1);
        SBODY(st + 2, cwB, cwA, 0);
        SBODY(st + 3, cwB, cwA, 1);
    }
    SBODY(16, cwA, cwB, 0);          // combines 32,33; stages A(17); issues 34,35
#undef SBODY

    // stage 17 tail: combine chunks 34,35 (tap 8 = cwA); no issues/staging.
    {
        cmbMfma(1, 0, GA0, GA1, GA2, GA3, cwA);
        cmbMfma(1, 1, GB0, GB1, GB2, GB3, cwA);
    }
#undef ISSUE

    // epilogue: C layout col(p)=lane&15, row(o)=(lane>>4)*4+reg.
    // af index I -> o-base = (I>>2)*64 + (I&3)*16 (w_t2 fragment order).
    int pgo = p0 + wv * 16 + lm;
    #pragma unroll
    for (int I = 0; I < 8; I++) {
        int ob = (I >> 2) * 64 + (I & 3) * 16 + lq * 4;
        #pragma unroll
        for (int r = 0; r < 4; r++) {
            int o = ob + r;
            float bv = bias[o];
            __builtin_nontemporal_store(acc[I][r] + bv,
                out + (size_t)(b * COUT_ + o) * HWp + pgo);
        }
    }
}

extern "C" void kernel_launch(void* const* d_in, const int* in_sizes, int n_in,
                              void* d_out, int out_size, void* d_ws, size_t ws_size,
                              hipStream_t stream) {
    const float* x     = (const float*)d_in[0];
    const float* w_off = (const float*)d_in[1];
    const float* b_off = (const float*)d_in[2];
    const float* w     = (const float*)d_in[3];
    const float* bias  = (const float*)d_in[4];
    float* out = (float*)d_out;

    char* ws = (char*)d_ws;
    ushort* xt   = (ushort*)ws;                          // 8 MiB (f16 NHWC)
    ushort* w_t2 = (ushort*)(ws + 8388608);              // 294912 B (f16 frag order)
    float4* der  = (float4*)(ws + 8683520);              // 512 KiB {sy,sx,sc1,sc2}/pos

    prep_offsets_kernel<<<1344, 256, 0, stream>>>(x, w, w_off, b_off,
                                                  xt, w_t2, der);
    deform_gemm_mfma<<<512, 256, 0, stream>>>(xt, w_t2, bias, der, out);
}

// Round 10
// 111.072 us; speedup vs baseline: 1.1770x; 1.1770x over previous
//
#include <hip/hip_runtime.h>

#define Wd 64
#define Hd 64
#define HWp 4096
#define CIN_ 128
#define COUT_ 128

typedef _Float16 f16;
typedef _Float16 h2    __attribute__((ext_vector_type(2)));
typedef _Float16 f16x8 __attribute__((ext_vector_type(8)));
typedef float f32x4    __attribute__((ext_vector_type(4)));

__device__ inline ushort f2h(float f) {
    f16 h = (f16)f;
    return __builtin_bit_cast(ushort, h);
}
__device__ inline h2 gb(const int4& g, int d) {
    return __builtin_bit_cast(h2, (&g.x)[d]);
}
__device__ inline h2 dup(float f) {
    f16 h = (f16)f;
    h2 r; r[0] = h; r[1] = h;
    return r;
}
struct H8 { h2 r[4]; };

// ---------------------------------------------------------------------------
// K_prep (1088 blocks):
//   blk 0..575   : repack main w -> f16 w_t2 in MFMA A-fragment order
//   blk 576..1087: offset conv (4 used ch) -> der[b][p] AND fused x-transpose:
//                  the conv already reads the full center row x[b,:,h,:]
//                  (tap 4) -> f2h it into an LDS tile and store one
//                  contiguous coalesced 16 KB block of xt. The standalone
//                  transpose pass (and its 64 MB x re-read) is deleted.
// ---------------------------------------------------------------------------
__global__ __launch_bounds__(256) void prep_offsets_kernel(
    const float* __restrict__ x, const float* __restrict__ w,
    const float* __restrict__ w_off, const float* __restrict__ b_off,
    ushort* __restrict__ xt, ushort* __restrict__ w_t2,
    float4* __restrict__ der)
{
    __shared__ char smem[39424];
    int blk = blockIdx.x;
    int t = threadIdx.x;

    if (blk < 576) {
        int i = blk * 256 + t;                       // 147456 total
        int j    = i & 7;
        int lane = (i >> 3) & 63;
        int ii   = (i >> 9) & 3;
        int wm   = (i >> 11) & 1;
        int s    = i >> 12;
        int o = wm * 64 + ii * 16 + (lane & 15);
        int c = (s & 3) * 32 + (lane >> 4) * 8 + j;
        int k = s >> 2;
        w_t2[i] = f2h(w[o * 1152 + c * 9 + k]);
    } else {
        float* wl    = (float*)smem;                  // 4608 f  (18432 B)
        float* part  = (float*)(smem + 18432);        // 1024 f  ( 4096 B)
        ushort* tile = (ushort*)(smem + 22528);       // [64][132] (16896 B)
        int blk2 = blk - 576;
        int b = blk2 >> 6;
        int h = blk2 & 63;

        for (int i = t; i < 4608; i += 256) {
            int j = i / 1152;
            int r = i - j * 1152;                     // c*9 + tap
            wl[r * 4 + j] = w_off[i];
        }
        __syncthreads();

        int pi = t & 63, cc = t >> 6;
        const float* xb = x + (size_t)(b * CIN_ + cc * 32) * HWp;

        int idx9[9];
        float msk9[9];
        #pragma unroll
        for (int dy = 0; dy < 3; dy++) {
            int hy = h + dy - 1;
            int hyc = min(max(hy, 0), Hd - 1);
            bool vr = (hy >= 0) && (hy < Hd);
            #pragma unroll
            for (int dx = 0; dx < 3; dx++) {
                int wx = pi + dx - 1;
                int wxc = min(max(wx, 0), Wd - 1);
                bool v = vr && (wx >= 0) && (wx < Wd);
                idx9[dy * 3 + dx] = hyc * Wd + wxc;
                msk9[dy * 3 + dx] = v ? 1.0f : 0.0f;
            }
        }

        float o0 = 0.f, o1 = 0.f, o2 = 0.f, o3 = 0.f;
        #pragma unroll 2
        for (int c4 = 0; c4 < 8; c4++) {
            ushort4 hv;
            #pragma unroll
            for (int j = 0; j < 4; j++) {
                int c = c4 * 4 + j;
                const float* xp = xb + c * HWp;
                const float* wc = &wl[(cc * 32 + c) * 36];
                float xv[9];
                #pragma unroll
                for (int tp = 0; tp < 9; tp++) xv[tp] = xp[idx9[tp]] * msk9[tp];
                (&hv.x)[j] = f2h(xv[4]);     // center tap: x[b, cc*32+c, h, pi]
                #pragma unroll
                for (int tp = 0; tp < 9; tp++) {
                    float4 wj = *(const float4*)&wc[tp * 4];
                    o0 += xv[tp] * wj.x; o1 += xv[tp] * wj.y;
                    o2 += xv[tp] * wj.z; o3 += xv[tp] * wj.w;
                }
            }
            *(ushort4*)&tile[pi * 132 + cc * 32 + c4 * 4] = hv;
        }
        part[t * 4 + 0] = o0;
        part[t * 4 + 1] = o1;
        part[t * 4 + 2] = o2;
        part[t * 4 + 3] = o3;
        __syncthreads();

        // fused transpose store: xt[b][h*64 .. h*64+63][0..127] is one
        // contiguous 16 KB region -> 4 fully-coalesced int4 stores/thread.
        {
            ushort* dst = xt + ((size_t)b * HWp + h * 64) * CIN_;
            #pragma unroll
            for (int k = 0; k < 4; k++) {
                int q = t + k * 256;                 // int4 index, 1024 total
                int row = q >> 4, c16 = q & 15;
                int4 v = *(const int4*)&tile[row * 132 + c16 * 8];
                *(int4*)(dst + q * 8) = v;
            }
        }

        if (t < 64) {
            float s0 = b_off[0], s1 = b_off[1], s2 = b_off[2], s3 = b_off[3];
            #pragma unroll
            for (int q = 0; q < 4; q++) {
                s0 += part[(q * 64 + t) * 4 + 0];
                s1 += part[(q * 64 + t) * 4 + 1];
                s2 += part[(q * 64 + t) * 4 + 2];
                s3 += part[(q * 64 + t) * 4 + 3];
            }
            float4 d;
            d.x = s0;
            d.y = s1;
            d.z = fmaxf(s2, 0.f) + 1.f;
            d.w = fmaxf(s3, 0.f) + 1.f;
            der[(size_t)b * HWp + h * Wd + t] = d;
        }
    }
}

// ---------------------------------------------------------------------------
// K3: round-5 version VERBATIM (measured best: ~30 us standalone).
// fused gather + f16 MFMA GEMM, BK=64 stages, depth-2 gather prefetch,
// S_lds staging, LDS meta tables, 256-thr blocks, 2 blocks/CU, XCD swizzle.
// (S-free register-B variants of r6-r8 measured 45 us -> permanently
// reverted: the S_lds round-trip is cheaper than its removal.)
// ---------------------------------------------------------------------------
__global__ __launch_bounds__(256, 2) void deform_gemm_mfma(
    const ushort* __restrict__ xt, const ushort* __restrict__ w_t2,
    const float* __restrict__ bias, const float4* __restrict__ der,
    float* __restrict__ out)
{
    __shared__ ushort A_lds[2][2][4096];      // 32 KiB (full M=128 x 64c)
    __shared__ ushort S_lds[2][2][64 * 40];   // 20 KiB
    __shared__ int4 MI[9][64];                // 9 KiB corner byte-offsets
    __shared__ int4 MW[9][64];                // 9 KiB dup-f16 weights (H8)

    int t = threadIdx.x;
    int b = blockIdx.x & 7;                   // XCD-local batch
    int rp = blockIdx.x >> 3;                 // 0..63
    int p0 = rp << 6;
    const char* xtb = (const char*)(xt + (size_t)b * HWp * CIN_);

    int p  = t >> 2;                 // 0..63 position in tile
    int c8 = (t & 3) << 3;           // channel offset in 32-chunk
    int c8b = c8 * 2;                // bytes

    int wv = t >> 6, lane = t & 63;  // 4 waves
    int wm = wv & 1, ns = wv >> 1;   // M-half, N-32-seg (0..1)
    int lm = lane & 15, lq = lane >> 4;

    f32x4 acc[4][2] = {};

    // ---- one-time meta: 4 threads per p split the 9 taps -------------------
    {
        int pg = p0 + p;
        float fh = (float)(pg >> 6), fp = (float)(pg & 63);
        float4 dv = der[(size_t)b * HWp + pg];   // {sy, sx, sc1, sc2}
        for (int k = (t & 3); k < 9; k += 4) {
            int ky = (k * 11) >> 5;              // k/3 for 0..8
            int kx = k - ky * 3;
            float by = (float)(ky - 1), bx = (float)(kx - 1);
            bool corner = (ky != 1) && (kx != 1);
            bool edge = (ky != 1) ^ (kx != 1);
            float sk = corner ? dv.z : (edge ? dv.w : 0.0f);
            float py = fh + by * sk + dv.x;
            float px = fp + bx * sk + dv.y;
            float y0f = floorf(py), x0f = floorf(px);
            float wy = py - y0f, wx = px - x0f;
            int y0 = (int)y0f, x0 = (int)x0f;
            int y1 = y0 + 1, x1 = x0 + 1;
            float vy0 = (y0 >= 0 && y0 < Hd) ? 1.f : 0.f;
            float vy1 = (y1 >= 0 && y1 < Hd) ? 1.f : 0.f;
            float vx0 = (x0 >= 0 && x0 < Wd) ? 1.f : 0.f;
            float vx1 = (x1 >= 0 && x1 < Wd) ? 1.f : 0.f;
            int cy0 = min(max(y0, 0), Hd - 1), cy1 = min(max(y1, 0), Hd - 1);
            int cx0 = min(max(x0, 0), Wd - 1), cx1 = min(max(x1, 0), Wd - 1);
            int4 ii;
            ii.x = (cy0 * Wd + cx0) << 8;        // * CIN_ * 2 bytes
            ii.y = (cy0 * Wd + cx1) << 8;
            ii.z = (cy1 * Wd + cx0) << 8;
            ii.w = (cy1 * Wd + cx1) << 8;
            MI[k][p] = ii;
            H8 hw;
            hw.r[0] = dup((1.f - wy) * (1.f - wx) * vy0 * vx0);
            hw.r[1] = dup((1.f - wy) * wx * vy0 * vx1);
            hw.r[2] = dup(wy * (1.f - wx) * vy1 * vx0);
            hw.r[3] = dup(wy * wx * vy1 * vx1);
            MW[k][p] = __builtin_bit_cast(int4, hw);
        }
    }
    __syncthreads();

    int vo0, vo1, vo2, vo3;          // gather byte offsets (current tap)

    // async A staging: stage st covers w_t2 ushorts [st*8192, st*8192+8192).
    auto stageA = [&](int buf, int st) {
        const ushort* src = w_t2 + (size_t)st * 8192;
        #pragma unroll
        for (int cc = 0; cc < 2; cc++) {
            #pragma unroll
            for (int hrow = 0; hrow < 2; hrow++) {
                const ushort* g = src + cc * 4096 + (wv * 2 + hrow) * 512 + lane * 8;
                ushort* l = &A_lds[buf][cc][(wv * 2 + hrow) * 512];
                __builtin_amdgcn_global_load_lds(
                    (const __attribute__((address_space(1))) unsigned int*)g,
                    (__attribute__((address_space(3))) unsigned int*)l, 16, 0, 0);
            }
        }
    };

    auto issue = [&](int st, int4 (&G)[2][4]) {
        #pragma unroll
        for (int cc = 0; cc < 2; cc++) {
            int q = (2 * st + cc) & 3;
            G[cc][0] = *(const int4*)(xtb + (vo0 + q * 64));
            G[cc][1] = *(const int4*)(xtb + (vo1 + q * 64));
            G[cc][2] = *(const int4*)(xtb + (vo2 + q * 64));
            G[cc][3] = *(const int4*)(xtb + (vo3 + q * 64));
        }
    };
    auto commitS = [&](int buf, const int4 (&G)[2][4], const H8& cw) {
        #pragma unroll
        for (int cc = 0; cc < 2; cc++) {
            H8 tmp;
            #pragma unroll
            for (int d = 0; d < 4; d++) {
                h2 r = gb(G[cc][0], d) * cw.r[0];
                r = gb(G[cc][1], d) * cw.r[1] + r;
                r = gb(G[cc][2], d) * cw.r[2] + r;
                r = gb(G[cc][3], d) * cw.r[3] + r;
                tmp.r[d] = r;
            }
            *(int4*)&S_lds[buf][cc][p * 40 + c8] = __builtin_bit_cast(int4, tmp);
        }
    };
    auto mfmaSec = [&](int cur) {
        #pragma unroll
        for (int cc = 0; cc < 2; cc++) {
            f16x8 af[4], bfr[2];
            #pragma unroll
            for (int i = 0; i < 4; i++)
                af[i] = *(const f16x8*)&A_lds[cur][cc][(wm * 4 + i) * 512 + lane * 8];
            #pragma unroll
            for (int f = 0; f < 2; f++)
                bfr[f] = *(const f16x8*)&S_lds[cur][cc][(ns * 32 + f * 16 + lm) * 40 + lq * 8];
            #pragma unroll
            for (int i = 0; i < 4; i++)
                #pragma unroll
                for (int f = 0; f < 2; f++)
                    acc[i][f] = __builtin_amdgcn_mfma_f32_16x16x32_f16(
                        af[i], bfr[f], acc[i][f], 0, 0, 0);
        }
    };

    int4 GA[2][4], GB[2][4];          // G[s&1] holds gathers for stage s
    H8 cwA, cwB;
    int4 idxN;

    // prologue: A stage0; gathers stage0+stage1 (tap 0); commit stage0.
    stageA(0, 0);
    __builtin_amdgcn_sched_barrier(0);
    {
        int4 i0 = MI[0][p];
        vo0 = i0.x + c8b; vo1 = i0.y + c8b; vo2 = i0.z + c8b; vo3 = i0.w + c8b;
    }
    issue(0, GA);
    cwA = __builtin_bit_cast(H8, MW[0][p]);
    commitS(0, GA, cwA);              // compiler waits GA (drains stageA too)
    issue(1, GB);
    idxN = MI[1][p];                  // addrs for stages 2,3 (tap 1)
    asm volatile("s_waitcnt vmcnt(8) lgkmcnt(0)" ::: "memory");
    __builtin_amdgcn_s_barrier();
    __builtin_amdgcn_sched_barrier(0);

// Stage ST: commit stage ST+1 from GC (issued at ST-1), issue ST+2 into GI.
// DORD=1 on even stages: refresh gather addrs from idxN, then reload
// idxN (tap+2) and CWR (weights tap+1) from the LDS tables (clamped; the
// clamped tail reads are never consumed).
#define BODY(ST, GC, GI, CWC, CWR, DORD)                                     \
    {                                                                        \
        int cur_ = (ST) & 1, nb_ = cur_ ^ 1;                                 \
        if ((ST) + 1 < 18) stageA(nb_, (ST) + 1);                            \
        __builtin_amdgcn_sched_barrier(0);                                   \
        if ((ST) + 2 < 18) {                                                 \
            if (DORD) {                                                      \
                vo0 = idxN.x + c8b; vo1 = idxN.y + c8b;                      \
                vo2 = idxN.z + c8b; vo3 = idxN.w + c8b;                      \
            }                                                                \
            issue((ST) + 2, GI);                                             \
        }                                                                    \
        if (DORD) {                                                          \
            idxN = MI[min(((ST) >> 1) + 2, 8)][p];                           \
            CWR = __builtin_bit_cast(H8, MW[min(((ST) >> 1) + 1, 8)][p]);    \
        }                                                                    \
        __builtin_amdgcn_s_setprio(1);                                       \
        mfmaSec(cur_);                                                       \
        __builtin_amdgcn_s_setprio(0);                                       \
        if ((ST) + 1 < 18) commitS(nb_, GC, CWC);                            \
        if ((ST) + 2 < 18) {                                                 \
            asm volatile("s_waitcnt vmcnt(8) lgkmcnt(0)" ::: "memory");      \
        } else {                                                             \
            asm volatile("s_waitcnt vmcnt(0) lgkmcnt(0)" ::: "memory");      \
        }                                                                    \
        __builtin_amdgcn_s_barrier();                                        \
        __builtin_amdgcn_sched_barrier(0);                                   \
    }

    for (int su = 0; su < 4; su++) {
        int st = su << 2;
        BODY(st,     GB, GA, cwA, cwB, 1);
        BODY(st + 1, GA, GB, cwB, cwB, 0);
        BODY(st + 2, GB, GA, cwB, cwA, 1);
        BODY(st + 3, GA, GB, cwA, cwA, 0);
    }
    BODY(16, GB, GA, cwA, cwB, 1);
    BODY(17, GA, GB, cwB, cwB, 0);
#undef BODY

    // epilogue: C layout col(p)=lane&15, row(o)=(lane>>4)*4+reg
    #pragma unroll
    for (int i = 0; i < 4; i++) {
        #pragma unroll
        for (int r = 0; r < 4; r++) {
            int o = wm * 64 + i * 16 + lq * 4 + r;
            float bv = bias[o];
            float* orow = out + (size_t)(b * COUT_ + o) * HWp + p0 + ns * 32 + lm;
            #pragma unroll
            for (int f = 0; f < 2; f++)
                __builtin_nontemporal_store(acc[i][f][r] + bv, &orow[f * 16]);
        }
    }
}

extern "C" void kernel_launch(void* const* d_in, const int* in_sizes, int n_in,
                              void* d_out, int out_size, void* d_ws, size_t ws_size,
                              hipStream_t stream) {
    const float* x     = (const float*)d_in[0];
    const float* w_off = (const float*)d_in[1];
    const float* b_off = (const float*)d_in[2];
    const float* w     = (const float*)d_in[3];
    const float* bias  = (const float*)d_in[4];
    float* out = (float*)d_out;

    char* ws = (char*)d_ws;
    ushort* xt   = (ushort*)ws;                          // 8 MiB (f16 NHWC)
    ushort* w_t2 = (ushort*)(ws + 8388608);              // 294912 B (f16 frag order)
    float4* der  = (float4*)(ws + 8683520);              // 512 KiB {sy,sx,sc1,sc2}/pos

    prep_offsets_kernel<<<1088, 256, 0, stream>>>(x, w, w_off, b_off,
                                                  xt, w_t2, der);
    deform_gemm_mfma<<<512, 256, 0, stream>>>(xt, w_t2, bias, der, out);
}

// Round 11
// 108.730 us; speedup vs baseline: 1.2024x; 1.0215x over previous
//
#include <hip/hip_runtime.h>

#define Wd 64
#define Hd 64
#define HWp 4096
#define CIN_ 128
#define COUT_ 128

typedef _Float16 f16;
typedef _Float16 h2    __attribute__((ext_vector_type(2)));
typedef _Float16 f16x8 __attribute__((ext_vector_type(8)));
typedef float f32x4    __attribute__((ext_vector_type(4)));

__device__ inline ushort f2h(float f) {
    f16 h = (f16)f;
    return __builtin_bit_cast(ushort, h);
}
__device__ inline h2 gb(const int4& g, int d) {
    return __builtin_bit_cast(h2, (&g.x)[d]);
}
__device__ inline h2 dup(float f) {
    f16 h = (f16)f;
    h2 r; r[0] = h; r[1] = h;
    return r;
}
struct H8 { h2 r[4]; };

// ---------------------------------------------------------------------------
// K_prep (552 blocks, 512 threads):
//   blk 0..39  : repack main w -> f16 w_t2 (8 vals/thread, int4 stores;
//                padded to 40 blocks so conv blocks start XCD-aligned)
//   blk 40..551: offset conv + fused x-transpose.
//     - 512 thr, 16 ch/thread (was 256/32): 2x waves -> 4 waves/SIMD for
//       latency hiding of the 144 scalar gather loads per thread.
//     - XCD swizzle: b = blk2&7, h = blk2>>3 -> all blocks of batch b on
//       XCD b; x[b] = 2 MB fits the 4 MB private L2, halo rows (3x re-read
//       by adjacent h) become L2 hits.
// ---------------------------------------------------------------------------
__global__ __launch_bounds__(512) void prep_offsets_kernel(
    const float* __restrict__ x, const float* __restrict__ w,
    const float* __restrict__ w_off, const float* __restrict__ b_off,
    ushort* __restrict__ xt, ushort* __restrict__ w_t2,
    float4* __restrict__ der)
{
    __shared__ char smem[43520];
    int blk = blockIdx.x;
    int t = threadIdx.x;

    if (blk < 40) {
        int i8 = blk * 512 + t;                      // 18432 used
        if (i8 < 18432) {
            int lane = i8 & 63;
            int ii   = (i8 >> 6) & 3;
            int wm   = (i8 >> 8) & 1;
            int s    = i8 >> 9;
            int o  = wm * 64 + ii * 16 + (lane & 15);
            int cb = (s & 3) * 32 + (lane >> 4) * 8;
            int k  = s >> 2;
            ushort tmp[8];
            #pragma unroll
            for (int j = 0; j < 8; j++)
                tmp[j] = f2h(w[o * 1152 + (cb + j) * 9 + k]);
            *(int4*)&w_t2[(size_t)i8 * 8] = *(int4*)tmp;
        }
    } else {
        float* wl    = (float*)smem;                  // 4608 f  (18432 B)
        float* part  = (float*)(smem + 18432);        // 2048 f  ( 8192 B)
        ushort* tile = (ushort*)(smem + 26624);       // [64][132] (16896 B)
        int blk2 = blk - 40;
        int b = blk2 & 7;                             // XCD-local batch
        int h = blk2 >> 3;

        for (int i = t; i < 4608; i += 512) {
            int j = i / 1152;
            int r = i - j * 1152;                     // c*9 + tap
            wl[r * 4 + j] = w_off[i];
        }
        __syncthreads();

        int pi = t & 63, cg = t >> 6;                 // pos, 16-ch group 0..7
        const float* xb = x + (size_t)(b * CIN_ + cg * 16) * HWp;

        int idx9[9];
        float msk9[9];
        #pragma unroll
        for (int dy = 0; dy < 3; dy++) {
            int hy = h + dy - 1;
            int hyc = min(max(hy, 0), Hd - 1);
            bool vr = (hy >= 0) && (hy < Hd);
            #pragma unroll
            for (int dx = 0; dx < 3; dx++) {
                int wx = pi + dx - 1;
                int wxc = min(max(wx, 0), Wd - 1);
                bool v = vr && (wx >= 0) && (wx < Wd);
                idx9[dy * 3 + dx] = hyc * Wd + wxc;
                msk9[dy * 3 + dx] = v ? 1.0f : 0.0f;
            }
        }

        float o0 = 0.f, o1 = 0.f, o2 = 0.f, o3 = 0.f;
        #pragma unroll
        for (int c4 = 0; c4 < 4; c4++) {
            ushort4 hv;
            #pragma unroll
            for (int j = 0; j < 4; j++) {
                int c = c4 * 4 + j;
                const float* xp = xb + c * HWp;
                const float* wc = &wl[(cg * 16 + c) * 36];
                float xv[9];
                #pragma unroll
                for (int tp = 0; tp < 9; tp++) xv[tp] = xp[idx9[tp]] * msk9[tp];
                (&hv.x)[j] = f2h(xv[4]);     // center tap: x[b, cg*16+c, h, pi]
                #pragma unroll
                for (int tp = 0; tp < 9; tp++) {
                    float4 wj = *(const float4*)&wc[tp * 4];
                    o0 += xv[tp] * wj.x; o1 += xv[tp] * wj.y;
                    o2 += xv[tp] * wj.z; o3 += xv[tp] * wj.w;
                }
            }
            *(ushort4*)&tile[pi * 132 + cg * 16 + c4 * 4] = hv;
        }
        part[t * 4 + 0] = o0;
        part[t * 4 + 1] = o1;
        part[t * 4 + 2] = o2;
        part[t * 4 + 3] = o3;
        __syncthreads();

        // fused transpose store: xt[b][h*64 .. h*64+63][0..127] is one
        // contiguous 16 KB region -> 2 fully-coalesced int4 stores/thread.
        {
            ushort* dst = xt + ((size_t)b * HWp + h * 64) * CIN_;
            #pragma unroll
            for (int k = 0; k < 2; k++) {
                int q = t + k * 512;                 // int4 index, 1024 total
                int row = q >> 4, c16 = q & 15;
                int4 v = *(const int4*)&tile[row * 132 + c16 * 8];
                *(int4*)(dst + q * 8) = v;
            }
        }

        if (t < 64) {
            float s0 = b_off[0], s1 = b_off[1], s2 = b_off[2], s3 = b_off[3];
            #pragma unroll
            for (int q = 0; q < 8; q++) {
                s0 += part[(q * 64 + t) * 4 + 0];
                s1 += part[(q * 64 + t) * 4 + 1];
                s2 += part[(q * 64 + t) * 4 + 2];
                s3 += part[(q * 64 + t) * 4 + 3];
            }
            float4 d;
            d.x = s0;
            d.y = s1;
            d.z = fmaxf(s2, 0.f) + 1.f;
            d.w = fmaxf(s3, 0.f) + 1.f;
            der[(size_t)b * HWp + h * Wd + t] = d;
        }
    }
}

// ---------------------------------------------------------------------------
// K3: round-5 version VERBATIM (measured best: ~30 us standalone).
// fused gather + f16 MFMA GEMM, BK=64 stages, depth-2 gather prefetch,
// S_lds staging, LDS meta tables, 256-thr blocks, 2 blocks/CU, XCD swizzle.
// (S-free register-B variants of r6-r8 measured 45 us -> permanently
// reverted: the S_lds round-trip is cheaper than its removal.)
// ---------------------------------------------------------------------------
__global__ __launch_bounds__(256, 2) void deform_gemm_mfma(
    const ushort* __restrict__ xt, const ushort* __restrict__ w_t2,
    const float* __restrict__ bias, const float4* __restrict__ der,
    float* __restrict__ out)
{
    __shared__ ushort A_lds[2][2][4096];      // 32 KiB (full M=128 x 64c)
    __shared__ ushort S_lds[2][2][64 * 40];   // 20 KiB
    __shared__ int4 MI[9][64];                // 9 KiB corner byte-offsets
    __shared__ int4 MW[9][64];                // 9 KiB dup-f16 weights (H8)

    int t = threadIdx.x;
    int b = blockIdx.x & 7;                   // XCD-local batch
    int rp = blockIdx.x >> 3;                 // 0..63
    int p0 = rp << 6;
    const char* xtb = (const char*)(xt + (size_t)b * HWp * CIN_);

    int p  = t >> 2;                 // 0..63 position in tile
    int c8 = (t & 3) << 3;           // channel offset in 32-chunk
    int c8b = c8 * 2;                // bytes

    int wv = t >> 6, lane = t & 63;  // 4 waves
    int wm = wv & 1, ns = wv >> 1;   // M-half, N-32-seg (0..1)
    int lm = lane & 15, lq = lane >> 4;

    f32x4 acc[4][2] = {};

    // ---- one-time meta: 4 threads per p split the 9 taps -------------------
    {
        int pg = p0 + p;
        float fh = (float)(pg >> 6), fp = (float)(pg & 63);
        float4 dv = der[(size_t)b * HWp + pg];   // {sy, sx, sc1, sc2}
        for (int k = (t & 3); k < 9; k += 4) {
            int ky = (k * 11) >> 5;              // k/3 for 0..8
            int kx = k - ky * 3;
            float by = (float)(ky - 1), bx = (float)(kx - 1);
            bool corner = (ky != 1) && (kx != 1);
            bool edge = (ky != 1) ^ (kx != 1);
            float sk = corner ? dv.z : (edge ? dv.w : 0.0f);
            float py = fh + by * sk + dv.x;
            float px = fp + bx * sk + dv.y;
            float y0f = floorf(py), x0f = floorf(px);
            float wy = py - y0f, wx = px - x0f;
            int y0 = (int)y0f, x0 = (int)x0f;
            int y1 = y0 + 1, x1 = x0 + 1;
            float vy0 = (y0 >= 0 && y0 < Hd) ? 1.f : 0.f;
            float vy1 = (y1 >= 0 && y1 < Hd) ? 1.f : 0.f;
            float vx0 = (x0 >= 0 && x0 < Wd) ? 1.f : 0.f;
            float vx1 = (x1 >= 0 && x1 < Wd) ? 1.f : 0.f;
            int cy0 = min(max(y0, 0), Hd - 1), cy1 = min(max(y1, 0), Hd - 1);
            int cx0 = min(max(x0, 0), Wd - 1), cx1 = min(max(x1, 0), Wd - 1);
            int4 ii;
            ii.x = (cy0 * Wd + cx0) << 8;        // * CIN_ * 2 bytes
            ii.y = (cy0 * Wd + cx1) << 8;
            ii.z = (cy1 * Wd + cx0) << 8;
            ii.w = (cy1 * Wd + cx1) << 8;
            MI[k][p] = ii;
            H8 hw;
            hw.r[0] = dup((1.f - wy) * (1.f - wx) * vy0 * vx0);
            hw.r[1] = dup((1.f - wy) * wx * vy0 * vx1);
            hw.r[2] = dup(wy * (1.f - wx) * vy1 * vx0);
            hw.r[3] = dup(wy * wx * vy1 * vx1);
            MW[k][p] = __builtin_bit_cast(int4, hw);
        }
    }
    __syncthreads();

    int vo0, vo1, vo2, vo3;          // gather byte offsets (current tap)

    // async A staging: stage st covers w_t2 ushorts [st*8192, st*8192+8192).
    auto stageA = [&](int buf, int st) {
        const ushort* src = w_t2 + (size_t)st * 8192;
        #pragma unroll
        for (int cc = 0; cc < 2; cc++) {
            #pragma unroll
            for (int hrow = 0; hrow < 2; hrow++) {
                const ushort* g = src + cc * 4096 + (wv * 2 + hrow) * 512 + lane * 8;
                ushort* l = &A_lds[buf][cc][(wv * 2 + hrow) * 512];
                __builtin_amdgcn_global_load_lds(
                    (const __attribute__((address_space(1))) unsigned int*)g,
                    (__attribute__((address_space(3))) unsigned int*)l, 16, 0, 0);
            }
        }
    };

    auto issue = [&](int st, int4 (&G)[2][4]) {
        #pragma unroll
        for (int cc = 0; cc < 2; cc++) {
            int q = (2 * st + cc) & 3;
            G[cc][0] = *(const int4*)(xtb + (vo0 + q * 64));
            G[cc][1] = *(const int4*)(xtb + (vo1 + q * 64));
            G[cc][2] = *(const int4*)(xtb + (vo2 + q * 64));
            G[cc][3] = *(const int4*)(xtb + (vo3 + q * 64));
        }
    };
    auto commitS = [&](int buf, const int4 (&G)[2][4], const H8& cw) {
        #pragma unroll
        for (int cc = 0; cc < 2; cc++) {
            H8 tmp;
            #pragma unroll
            for (int d = 0; d < 4; d++) {
                h2 r = gb(G[cc][0], d) * cw.r[0];
                r = gb(G[cc][1], d) * cw.r[1] + r;
                r = gb(G[cc][2], d) * cw.r[2] + r;
                r = gb(G[cc][3], d) * cw.r[3] + r;
                tmp.r[d] = r;
            }
            *(int4*)&S_lds[buf][cc][p * 40 + c8] = __builtin_bit_cast(int4, tmp);
        }
    };
    auto mfmaSec = [&](int cur) {
        #pragma unroll
        for (int cc = 0; cc < 2; cc++) {
            f16x8 af[4], bfr[2];
            #pragma unroll
            for (int i = 0; i < 4; i++)
                af[i] = *(const f16x8*)&A_lds[cur][cc][(wm * 4 + i) * 512 + lane * 8];
            #pragma unroll
            for (int f = 0; f < 2; f++)
                bfr[f] = *(const f16x8*)&S_lds[cur][cc][(ns * 32 + f * 16 + lm) * 40 + lq * 8];
            #pragma unroll
            for (int i = 0; i < 4; i++)
                #pragma unroll
                for (int f = 0; f < 2; f++)
                    acc[i][f] = __builtin_amdgcn_mfma_f32_16x16x32_f16(
                        af[i], bfr[f], acc[i][f], 0, 0, 0);
        }
    };

    int4 GA[2][4], GB[2][4];          // G[s&1] holds gathers for stage s
    H8 cwA, cwB;
    int4 idxN;

    // prologue: A stage0; gathers stage0+stage1 (tap 0); commit stage0.
    stageA(0, 0);
    __builtin_amdgcn_sched_barrier(0);
    {
        int4 i0 = MI[0][p];
        vo0 = i0.x + c8b; vo1 = i0.y + c8b; vo2 = i0.z + c8b; vo3 = i0.w + c8b;
    }
    issue(0, GA);
    cwA = __builtin_bit_cast(H8, MW[0][p]);
    commitS(0, GA, cwA);              // compiler waits GA (drains stageA too)
    issue(1, GB);
    idxN = MI[1][p];                  // addrs for stages 2,3 (tap 1)
    asm volatile("s_waitcnt vmcnt(8) lgkmcnt(0)" ::: "memory");
    __builtin_amdgcn_s_barrier();
    __builtin_amdgcn_sched_barrier(0);

// Stage ST: commit stage ST+1 from GC (issued at ST-1), issue ST+2 into GI.
// DORD=1 on even stages: refresh gather addrs from idxN, then reload
// idxN (tap+2) and CWR (weights tap+1) from the LDS tables (clamped; the
// clamped tail reads are never consumed).
#define BODY(ST, GC, GI, CWC, CWR, DORD)                                     \
    {                                                                        \
        int cur_ = (ST) & 1, nb_ = cur_ ^ 1;                                 \
        if ((ST) + 1 < 18) stageA(nb_, (ST) + 1);                            \
        __builtin_amdgcn_sched_barrier(0);                                   \
        if ((ST) + 2 < 18) {                                                 \
            if (DORD) {                                                      \
                vo0 = idxN.x + c8b; vo1 = idxN.y + c8b;                      \
                vo2 = idxN.z + c8b; vo3 = idxN.w + c8b;                      \
            }                                                                \
            issue((ST) + 2, GI);                                             \
        }                                                                    \
        if (DORD) {                                                          \
            idxN = MI[min(((ST) >> 1) + 2, 8)][p];                           \
            CWR = __builtin_bit_cast(H8, MW[min(((ST) >> 1) + 1, 8)][p]);    \
        }                                                                    \
        __builtin_amdgcn_s_setprio(1);                                       \
        mfmaSec(cur_);                                                       \
        __builtin_amdgcn_s_setprio(0);                                       \
        if ((ST) + 1 < 18) commitS(nb_, GC, CWC);                            \
        if ((ST) + 2 < 18) {                                                 \
            asm volatile("s_waitcnt vmcnt(8) lgkmcnt(0)" ::: "memory");      \
        } else {                                                             \
            asm volatile("s_waitcnt vmcnt(0) lgkmcnt(0)" ::: "memory");      \
        }                                                                    \
        __builtin_amdgcn_s_barrier();                                        \
        __builtin_amdgcn_sched_barrier(0);                                   \
    }

    for (int su = 0; su < 4; su++) {
        int st = su << 2;
        BODY(st,     GB, GA, cwA, cwB, 1);
        BODY(st + 1, GA, GB, cwB, cwB, 0);
        BODY(st + 2, GB, GA, cwB, cwA, 1);
        BODY(st + 3, GA, GB, cwA, cwA, 0);
    }
    BODY(16, GB, GA, cwA, cwB, 1);
    BODY(17, GA, GB, cwB, cwB, 0);
#undef BODY

    // epilogue: C layout col(p)=lane&15, row(o)=(lane>>4)*4+reg
    #pragma unroll
    for (int i = 0; i < 4; i++) {
        #pragma unroll
        for (int r = 0; r < 4; r++) {
            int o = wm * 64 + i * 16 + lq * 4 + r;
            float bv = bias[o];
            float* orow = out + (size_t)(b * COUT_ + o) * HWp + p0 + ns * 32 + lm;
            #pragma unroll
            for (int f = 0; f < 2; f++)
                __builtin_nontemporal_store(acc[i][f][r] + bv, &orow[f * 16]);
        }
    }
}

extern "C" void kernel_launch(void* const* d_in, const int* in_sizes, int n_in,
                              void* d_out, int out_size, void* d_ws, size_t ws_size,
                              hipStream_t stream) {
    const float* x     = (const float*)d_in[0];
    const float* w_off = (const float*)d_in[1];
    const float* b_off = (const float*)d_in[2];
    const float* w     = (const float*)d_in[3];
    const float* bias  = (const float*)d_in[4];
    float* out = (float*)d_out;

    char* ws = (char*)d_ws;
    ushort* xt   = (ushort*)ws;                          // 8 MiB (f16 NHWC)
    ushort* w_t2 = (ushort*)(ws + 8388608);              // 294912 B (f16 frag order)
    float4* der  = (float4*)(ws + 8683520);              // 512 KiB {sy,sx,sc1,sc2}/pos

    prep_offsets_kernel<<<552, 512, 0, stream>>>(x, w, w_off, b_off,
                                                 xt, w_t2, der);
    deform_gemm_mfma<<<512, 256, 0, stream>>>(xt, w_t2, bias, der, out);
}